// Round 9
// baseline (250.345 us; speedup 1.0000x reference)
//
#include <hip/hip_runtime.h>
#include <hip/hip_bf16.h>

typedef __bf16 bf16x8 __attribute__((ext_vector_type(8)));
typedef __bf16 bf16x4 __attribute__((ext_vector_type(4)));
typedef float  f32x4  __attribute__((ext_vector_type(4)));

#define NB 4
#define TT 4096
#define CC 1024
#define HH 128
#define PS 72
#define MNEG -30000.0f

__device__ inline void gload16(const void* g, void* l) {
  __builtin_amdgcn_global_load_lds(
      (const __attribute__((address_space(1))) void*)g,
      (__attribute__((address_space(3))) void*)l, 16, 0, 0);
}

// ---- in-kernel dtype probe (replaces detect_dtype kernel; one fewer launch) ----
// Wave-uniform: every wave reads the same first 256 words of x, counts bf16-pair
// exponent signatures, 6-step shfl reduce. fp32 mantissa bits ~14% hit rate vs
// ~100% for bf16 pairs -> threshold 128/256 separates cleanly.
__device__ __forceinline__ int probe_isbf(const unsigned int* __restrict__ xw) {
  int lane = threadIdx.x & 63;
  int cnt = 0;
#pragma unroll
  for (int i = 0; i < 4; ++i) {
    unsigned int w = xw[lane + 64 * i];
    int e = (int)((w >> 7) & 0xFFu);
    cnt += (e >= 100 && e <= 135) ? 1 : 0;
  }
  cnt += __shfl_xor(cnt, 1);  cnt += __shfl_xor(cnt, 2);  cnt += __shfl_xor(cnt, 4);
  cnt += __shfl_xor(cnt, 8);  cnt += __shfl_xor(cnt, 16); cnt += __shfl_xor(cnt, 32);
  return cnt >= 128;
}

// -------- transpose W [C][H] -> proj-staging tile format, x3 --------
// layout: [kstep=c/64][which][g=(c/8)%8][h][j=c%8]
// h=idx&127: consecutive lanes -> consecutive h -> coalesced W read.
__global__ __launch_bounds__(256) void transpose_w3(
    const void* __restrict__ Wq, const void* __restrict__ Wk,
    const void* __restrict__ Wv, __bf16* __restrict__ Wt,
    const unsigned int* __restrict__ xw) {
  int isbf = probe_isbf(xw);
  int which = blockIdx.y;
  const void* W = (which == 0) ? Wq : (which == 1) ? Wk : Wv;
  int idx = blockIdx.x * 256 + threadIdx.x;
  int h = idx & 127, c = idx >> 7;
  __bf16 val;
  if (isbf) val = ((const __bf16*)W)[c * HH + h];
  else      val = (__bf16)(((const float*)W)[c * HH + h]);
  size_t o = (size_t)(c >> 6) * 24576 + (size_t)which * 8192 +
             (size_t)((c >> 3) & 7) * 1024 + (size_t)h * 8 + (c & 7);
  Wt[o] = val;
}

// ------- fused QKV projection: 12 waves, double-buffered staging -------
// 256 blocks x 768 thr (3 which x 4 rowgroups). M=64, BK=64, 16 K-steps.
// XT xor-swizzled granules; WTs streamed via global_load_lds.
__global__ __launch_bounds__(768) void qkv_proj(
    const void* __restrict__ x, const __bf16* __restrict__ Wt,
    __bf16* __restrict__ q, __bf16* __restrict__ ktl, __bf16* __restrict__ vtl) {
  __shared__ __align__(16) __bf16 XT[2][4096];     // 16 KB
  __shared__ __align__(16) __bf16 WTs[2][24576];   // 96 KB
  int isbf = probe_isbf((const unsigned int*)x);
  int tid = threadIdx.x, lane = tid & 63, wave = tid >> 6;
  int which = wave >> 2, rowgrp = wave & 3;
  int l16 = lane & 15, quad = lane >> 4;
  int row0 = blockIdx.x * 64;
  f32x4 acc[8] = {};

  // ---- staging helper (inlined twice): stage step ss into buffer b ----
#define STAGE(ss, b)                                                          \
  for (int i = wave; i < 56; i += 12) {                                       \
    if (i < 8) {                                                              \
      int row = i * 8 + (lane >> 3), g = lane & 7;                            \
      bf16x8 pk;                                                              \
      if (isbf) {                                                             \
        pk = *(const bf16x8*)((const __bf16*)x + (size_t)(row0 + row) * CC +  \
                              (ss) * 64 + g * 8);                             \
      } else {                                                                \
        const float* xf = (const float*)x + (size_t)(row0 + row) * CC +       \
                          (ss) * 64 + g * 8;                                  \
        f32x4 lo = *(const f32x4*)xf;                                         \
        f32x4 hi = *(const f32x4*)(xf + 4);                                   \
        for (int j = 0; j < 4; ++j) { pk[j] = (__bf16)lo[j]; pk[j+4] = (__bf16)hi[j]; } \
      }                                                                       \
      *(bf16x8*)(&XT[b][g * 512 + (row ^ g) * 8]) = pk;                       \
    } else {                                                                  \
      int j = i - 8;                                                          \
      gload16(Wt + (size_t)(ss) * 24576 + j * 512 + lane * 8,                 \
              &WTs[b][j * 512]);                                              \
    }                                                                         \
  }

  STAGE(0, 0);                           // preload step 0
  for (int s = 0; s < 16; ++s) {
    int cb = s & 1;
    __syncthreads();                     // must drain vmcnt here (global_load_lds -> LDS)
    if (s + 1 < 16) { STAGE(s + 1, cb ^ 1); }
#pragma unroll
    for (int t = 0; t < 2; ++t) {
      int g = t * 4 + quad;
      bf16x8 a = *(const bf16x8*)(&XT[cb][g * 512 + ((rowgrp * 16 + l16) ^ g) * 8]);
#pragma unroll
      for (int nt = 0; nt < 8; ++nt) {
        bf16x8 b = *(const bf16x8*)(&WTs[cb][(size_t)which * 8192 + g * 1024 + (nt * 16 + l16) * 8]);
        acc[nt] = __builtin_amdgcn_mfma_f32_16x16x32_bf16(a, b, acc[nt], 0, 0, 0);
      }
    }
  }
#undef STAGE

  int tile = row0 >> 6;
  if (which == 0) {
#pragma unroll
    for (int nt = 0; nt < 8; ++nt)
#pragma unroll
      for (int r = 0; r < 4; ++r) {
        int row = row0 + rowgrp * 16 + quad * 4 + r;
        q[(size_t)row * HH + nt * 16 + l16] = (__bf16)acc[nt][r];
      }
  } else if (which == 1) {
    __bf16* kb = ktl + (size_t)tile * 8192;
#pragma unroll
    for (int nt = 0; nt < 8; ++nt) {
      int h = nt * 16 + l16, g = h >> 3, j = h & 7;
#pragma unroll
      for (int r = 0; r < 4; ++r) {
        int sidx = rowgrp * 16 + quad * 4 + r;
        kb[g * 512 + sidx * 8 + j] = (__bf16)acc[nt][r];
      }
    }
  } else {
    __bf16* vb = vtl + (size_t)tile * 8192;
#pragma unroll
    for (int nt = 0; nt < 8; ++nt) {
      int h = nt * 16 + l16;
      int sb = rowgrp * 16 + quad * 4;
      bf16x4 pk;
#pragma unroll
      for (int r = 0; r < 4; ++r) pk[r] = (__bf16)acc[nt][r];
      *(bf16x4*)(vb + (sb >> 3) * 1024 + h * 8 + (sb & 7)) = pk;
    }
  }
}

// ------- flash attention: cooperative-pair split-K, software-pipelined -------
// Round-8 lesson: halving L1 bytes (4.16->2.2 MB/CU) moved time only 4% -- the
// kernel is latency/sync-bound: __syncthreads drains vmcnt(0) every iteration,
// exposing full K/V load latency on each of ~12 barrier-coupled iterations.
// This round: (a) prefetch K(t+1) into kf right after QK(t) consumes it, and
// V(t+1) into vf right after PV(t); (b) replace __syncthreads with
// lgkmcnt(0)-only + raw s_barrier + sched_barrier(0) -- global loads stay in
// flight ACROSS the barrier (they target registers, so no vmcnt drain is needed
// for the LDS P-exchange protocol; dbuf WAR analysis unchanged from round 8).
// K/V latency now rides under softmax+barrier+PV of the previous tile.
// Structure kept: pairs share P via LDS (16 KB/pair-tile), two-unit balance,
// XCD-batch swizzle, fixed-max softmax with plain-sum combine.
__global__ __launch_bounds__(768, 3) void flash_attn(
    const __bf16* __restrict__ q, const __bf16* __restrict__ ktl,
    const __bf16* __restrict__ vtl, void* __restrict__ out,
    const unsigned int* __restrict__ xw) {
  __shared__ __align__(16) __bf16 PLs[6][2][32 * PS]; // pair-shared P, dbuf, 55.3 KB
  __shared__ float CMB[4][32][132];                   // 4 partial-O sets, 67.6 KB
  __shared__ float CL[4][32];                         // partial l per set

  int bx = blockIdx.x;
  int batch = (bx & 7) >> 1;
  int qt0 = ((bx >> 3) << 1) | (bx & 1);

  int tid = threadIdx.x, lane = tid & 63, wave = tid >> 6;
  int p = wave >> 1, rw = wave & 1;      // 6 pairs x 2 col-half waves
  int l16 = lane & 15, quad = lane >> 4;

  int kA = (6 * (qt0 + 1) + 32) / 65;
  kA = max(1, min(5, kA));
  int qtB = 63 - qt0;
  int unit, kg, nkg, qtu, rbase;
  if (p < kA) { unit = 0; kg = p;      nkg = kA;     qtu = qt0; rbase = 0;  }
  else        { unit = 1; kg = p - kA; nkg = 6 - kA; qtu = qtB; rbase = 32; }

  int qb = qtu * 64;
  int MAXT = max(qt0 / kA + 1, qtB / (6 - kA) + 1);
  int mytrips = (qtu - kg) / nkg + 1;

  int isbf = probe_isbf(xw);

  const __bf16* qp  = q   + (size_t)batch * TT * HH;
  const __bf16* ktb = ktl + (size_t)batch * TT * HH;
  const __bf16* vtb = vtl + (size_t)batch * TT * HH;

  // Q fragments for all 32 rows of this unit (rows rbase..rbase+31)
  bf16x8 qf[2][4];
#pragma unroll
  for (int rg = 0; rg < 2; ++rg) {
    const __bf16* qrow = qp + (size_t)(qb + rbase + rg * 16 + l16) * HH + quad * 8;
#pragma unroll
    for (int ks = 0; ks < 4; ++ks) qf[rg][ks] = *(const bf16x8*)(qrow + ks * 32);
  }
  bf16x8 onesf;
#pragma unroll
  for (int j = 0; j < 8; ++j) onesf[j] = (l16 == 0) ? (__bf16)1.0f : (__bf16)0.0f;

  f32x4 acc_o[2][4] = {};                // [rowhalf][h-subtile within my 64-col half]
  f32x4 acc_l[2] = {};
  const float SC = 0.0450842200278f;     // log2(e)/32
  const float M0 = 4.0f;

  // ---- preload tile(kg) into kf/vf (t=0 operands in flight before loop) ----
  bf16x8 kf[4][2];
  bf16x8 vf[2][4];
  {
    const __bf16* kt0 = ktb + (size_t)kg * 8192;
#pragma unroll
    for (int ks = 0; ks < 4; ++ks)
#pragma unroll
      for (int kn = 0; kn < 2; ++kn)
        kf[ks][kn] = *(const bf16x8*)(kt0 + ((4 * ks + quad) * 64 + (rw * 2 + kn) * 16 + l16) * 8);
    const __bf16* vt0 = vtb + (size_t)kg * 8192;
#pragma unroll
    for (int ks2 = 0; ks2 < 2; ++ks2)
#pragma unroll
      for (int nt = 0; nt < 4; ++nt)
        vf[ks2][nt] = *(const bf16x8*)(vt0 + (ks2 * 4 + quad) * 1024 + (rw * 64 + nt * 16 + l16) * 8);
  }

  for (int t = 0; t < MAXT; ++t) {
    int jt = kg + t * nkg;
    int valid = (t < mytrips);
    int jn = (t + 1 < mytrips) ? (kg + (t + 1) * nkg) : kg;  // next tile (clamped)

    // QK^T for all 32 rows x my 32 k-cols (kf prefetched last iter)
    f32x4 accs[2][2] = {};
#pragma unroll
    for (int ks = 0; ks < 4; ++ks)
#pragma unroll
      for (int rg = 0; rg < 2; ++rg)
#pragma unroll
        for (int kn = 0; kn < 2; ++kn)
          accs[rg][kn] = __builtin_amdgcn_mfma_f32_16x16x32_bf16(qf[rg][ks], kf[ks][kn], accs[rg][kn], 0, 0, 0);

    // prefetch K(t+1) into kf (dead after QK); latency hides under
    // softmax + barrier + PV + next-iter start
    {
      const __bf16* ktn = ktb + (size_t)jn * 8192;
#pragma unroll
      for (int ks = 0; ks < 4; ++ks)
#pragma unroll
        for (int kn = 0; kn < 2; ++kn)
          kf[ks][kn] = *(const bf16x8*)(ktn + ((4 * ks + quad) * 64 + (rw * 2 + kn) * 16 + l16) * 8);
    }

    // fixed-max softmax: p = exp2(s*SC - M0); mask only on diagonal tile
    float pv[2][2][4];
    if (valid && jt == qtu) {
#pragma unroll
      for (int rg = 0; rg < 2; ++rg)
#pragma unroll
        for (int kn = 0; kn < 2; ++kn) {
          int kcol = jt * 64 + (rw * 2 + kn) * 16 + l16;
          int qr0 = qb + rbase + rg * 16 + quad * 4;
#pragma unroll
          for (int r = 0; r < 4; ++r) {
            float z = fmaf(accs[rg][kn][r], SC, -M0);
            z = (kcol <= qr0 + r) ? z : MNEG;
            pv[rg][kn][r] = exp2f(z);
          }
        }
    } else if (valid) {
#pragma unroll
      for (int rg = 0; rg < 2; ++rg)
#pragma unroll
        for (int kn = 0; kn < 2; ++kn)
#pragma unroll
          for (int r = 0; r < 4; ++r)
            pv[rg][kn][r] = exp2f(fmaf(accs[rg][kn][r], SC, -M0));
    } else {
#pragma unroll
      for (int rg = 0; rg < 2; ++rg)
#pragma unroll
        for (int kn = 0; kn < 2; ++kn)
#pragma unroll
          for (int r = 0; r < 4; ++r)
            pv[rg][kn][r] = 0.0f;        // padded iter contributes nothing
    }

    // my P-half -> pair-shared LDS (32 rows x my 32 cols), buffer t&1
    __bf16* pw = &PLs[p][t & 1][0];
#pragma unroll
    for (int rg = 0; rg < 2; ++rg)
#pragma unroll
      for (int kn = 0; kn < 2; ++kn)
#pragma unroll
        for (int r = 0; r < 4; ++r)
          pw[(rg * 16 + quad * 4 + r) * PS + (rw * 2 + kn) * 16 + l16] = (__bf16)pv[rg][kn][r];

    // non-draining barrier: LDS writes drained (lgkm), global prefetches
    // stay in flight across it (no vmcnt drain -- the whole point).
    asm volatile("s_waitcnt lgkmcnt(0)" ::: "memory");
    __builtin_amdgcn_s_barrier();
    __builtin_amdgcn_sched_barrier(0);

    // PV: all 32 rows (full P from LDS) x my 64 h-cols (vf prefetched last iter)
#pragma unroll
    for (int ks2 = 0; ks2 < 2; ++ks2) {
      bf16x8 pa0 = *(const bf16x8*)(pw + l16 * PS + ks2 * 32 + quad * 8);
      bf16x8 pa1 = *(const bf16x8*)(pw + (16 + l16) * PS + ks2 * 32 + quad * 8);
      acc_l[0] = __builtin_amdgcn_mfma_f32_16x16x32_bf16(pa0, onesf, acc_l[0], 0, 0, 0);
      acc_l[1] = __builtin_amdgcn_mfma_f32_16x16x32_bf16(pa1, onesf, acc_l[1], 0, 0, 0);
#pragma unroll
      for (int nt = 0; nt < 4; ++nt) {
        acc_o[0][nt] = __builtin_amdgcn_mfma_f32_16x16x32_bf16(pa0, vf[ks2][nt], acc_o[0][nt], 0, 0, 0);
        acc_o[1][nt] = __builtin_amdgcn_mfma_f32_16x16x32_bf16(pa1, vf[ks2][nt], acc_o[1][nt], 0, 0, 0);
      }
    }

    // prefetch V(t+1) into vf (dead after PV)
    {
      const __bf16* vtn = vtb + (size_t)jn * 8192;
#pragma unroll
      for (int ks2 = 0; ks2 < 2; ++ks2)
#pragma unroll
        for (int nt = 0; nt < 4; ++nt)
          vf[ks2][nt] = *(const bf16x8*)(vtn + (ks2 * 4 + quad) * 1024 + (rw * 64 + nt * 16 + l16) * 8);
    }
  }

  // ---- combine partials across pairs (plain sums; fixed-max => no rescale) ----
  // Slot map: unit A kg 1..kA-1 -> slots 0..kA-2; unit B kg 1..kB-1 -> kA-1..3.
  if (kg > 0) {
    int slot = (unit == 0) ? (kg - 1) : (kA - 1 + kg - 1);
#pragma unroll
    for (int rh = 0; rh < 2; ++rh)
#pragma unroll
      for (int nt = 0; nt < 4; ++nt)
#pragma unroll
        for (int r = 0; r < 4; ++r)
          CMB[slot][rh * 16 + quad * 4 + r][rw * 64 + nt * 16 + l16] = acc_o[rh][nt][r];
    if (rw == 0 && l16 == 0) {
#pragma unroll
      for (int rh = 0; rh < 2; ++rh)
#pragma unroll
        for (int r = 0; r < 4; ++r) CL[slot][rh * 16 + quad * 4 + r] = acc_l[rh][r];
    }
  }
  __syncthreads();
  if (kg == 0) {
    int lo  = (unit == 0) ? 0 : kA - 1;
    int cnt = (unit == 0) ? kA - 1 : 5 - kA;
    __bf16* ob = (__bf16*)out + (size_t)batch * TT * HH;
    float*  of = (float*)out  + (size_t)batch * TT * HH;
#pragma unroll
    for (int rh = 0; rh < 2; ++rh) {
      float inv[4];
#pragma unroll
      for (int r = 0; r < 4; ++r) {
        float lr = __shfl(acc_l[rh][r], lane & 48);
        for (int c = 0; c < cnt; ++c) lr += CL[lo + c][rh * 16 + quad * 4 + r];
        inv[r] = 1.f / fmaxf(lr, 1e-30f);
      }
#pragma unroll
      for (int nt = 0; nt < 4; ++nt)
#pragma unroll
        for (int r = 0; r < 4; ++r) {
          int row = qb + rbase + rh * 16 + quad * 4 + r;
          int col = rw * 64 + nt * 16 + l16;
          float val = acc_o[rh][nt][r];
          for (int c = 0; c < cnt; ++c) val += CMB[lo + c][rh * 16 + quad * 4 + r][col];
          val *= inv[r];
          size_t idx = (size_t)row * HH + col;
          if (isbf) ob[idx] = (__bf16)val;
          else      of[idx] = val;
        }
    }
  }
}

extern "C" void kernel_launch(void* const* d_in, const int* in_sizes, int n_in,
                              void* d_out, int out_size, void* d_ws, size_t ws_size,
                              hipStream_t stream) {
  const void* x  = d_in[0];
  const void* Wq = d_in[1];
  const void* Wk = d_in[2];
  const void* Wv = d_in[3];
  char* wsb = (char*)d_ws;
  __bf16* q   = (__bf16*)wsb;
  __bf16* ktl = q   + (size_t)NB * TT * HH;
  __bf16* vtl = ktl + (size_t)NB * TT * HH;
  __bf16* wt  = vtl + (size_t)NB * TT * HH;
  (void)ws_size; (void)in_sizes; (void)n_in; (void)out_size;

  transpose_w3<<<dim3(512, 3), 256, 0, stream>>>(Wq, Wk, Wv, wt,
                                                 (const unsigned int*)x);
  qkv_proj<<<256, 768, 0, stream>>>(x, wt, q, ktl, vtl);
  flash_attn<<<NB * 64, 768, 0, stream>>>(q, ktl, vtl, d_out,
                                          (const unsigned int*)x);
}

// Round 10
// 172.376 us; speedup vs baseline: 1.4523x; 1.4523x over previous
//
#include <hip/hip_runtime.h>
#include <hip/hip_bf16.h>

typedef __bf16 bf16x8 __attribute__((ext_vector_type(8)));
typedef __bf16 bf16x4 __attribute__((ext_vector_type(4)));
typedef float  f32x4  __attribute__((ext_vector_type(4)));

#define NB 4
#define TT 4096
#define CC 1024
#define HH 128
#define PS 72
#define MNEG -30000.0f

__device__ inline void gload16(const void* g, void* l) {
  __builtin_amdgcn_global_load_lds(
      (const __attribute__((address_space(1))) void*)g,
      (__attribute__((address_space(3))) void*)l, 16, 0, 0);
}

// ---- in-kernel dtype probe (replaces detect_dtype kernel; one fewer launch) ----
__device__ __forceinline__ int probe_isbf(const unsigned int* __restrict__ xw) {
  int lane = threadIdx.x & 63;
  int cnt = 0;
#pragma unroll
  for (int i = 0; i < 4; ++i) {
    unsigned int w = xw[lane + 64 * i];
    int e = (int)((w >> 7) & 0xFFu);
    cnt += (e >= 100 && e <= 135) ? 1 : 0;
  }
  cnt += __shfl_xor(cnt, 1);  cnt += __shfl_xor(cnt, 2);  cnt += __shfl_xor(cnt, 4);
  cnt += __shfl_xor(cnt, 8);  cnt += __shfl_xor(cnt, 16); cnt += __shfl_xor(cnt, 32);
  return cnt >= 128;
}

// -------- transpose W [C][H] -> proj-staging tile format, x3 --------
// layout: [kstep=c/64][which][g=(c/8)%8][h][j=c%8]
// h=idx&127: consecutive lanes -> consecutive h -> coalesced W read.
__global__ __launch_bounds__(256) void transpose_w3(
    const void* __restrict__ Wq, const void* __restrict__ Wk,
    const void* __restrict__ Wv, __bf16* __restrict__ Wt,
    const unsigned int* __restrict__ xw) {
  int isbf = probe_isbf(xw);
  int which = blockIdx.y;
  const void* W = (which == 0) ? Wq : (which == 1) ? Wk : Wv;
  int idx = blockIdx.x * 256 + threadIdx.x;
  int h = idx & 127, c = idx >> 7;
  __bf16 val;
  if (isbf) val = ((const __bf16*)W)[c * HH + h];
  else      val = (__bf16)(((const float*)W)[c * HH + h]);
  size_t o = (size_t)(c >> 6) * 24576 + (size_t)which * 8192 +
             (size_t)((c >> 3) & 7) * 1024 + (size_t)h * 8 + (c & 7);
  Wt[o] = val;
}

// ------- fused QKV projection: 12 waves, double-buffered staging -------
// 256 blocks x 768 thr (3 which x 4 rowgroups). M=64, BK=64, 16 K-steps.
// XT xor-swizzled granules; WTs streamed via global_load_lds.
__global__ __launch_bounds__(768) void qkv_proj(
    const void* __restrict__ x, const __bf16* __restrict__ Wt,
    __bf16* __restrict__ q, __bf16* __restrict__ ktl, __bf16* __restrict__ vtl) {
  __shared__ __align__(16) __bf16 XT[2][4096];     // 16 KB
  __shared__ __align__(16) __bf16 WTs[2][24576];   // 96 KB
  int isbf = probe_isbf((const unsigned int*)x);
  int tid = threadIdx.x, lane = tid & 63, wave = tid >> 6;
  int which = wave >> 2, rowgrp = wave & 3;
  int l16 = lane & 15, quad = lane >> 4;
  int row0 = blockIdx.x * 64;
  f32x4 acc[8] = {};

  // ---- staging helper (inlined twice): stage step ss into buffer b ----
#define STAGE(ss, b)                                                          \
  for (int i = wave; i < 56; i += 12) {                                       \
    if (i < 8) {                                                              \
      int row = i * 8 + (lane >> 3), g = lane & 7;                            \
      bf16x8 pk;                                                              \
      if (isbf) {                                                             \
        pk = *(const bf16x8*)((const __bf16*)x + (size_t)(row0 + row) * CC +  \
                              (ss) * 64 + g * 8);                             \
      } else {                                                                \
        const float* xf = (const float*)x + (size_t)(row0 + row) * CC +       \
                          (ss) * 64 + g * 8;                                  \
        f32x4 lo = *(const f32x4*)xf;                                         \
        f32x4 hi = *(const f32x4*)(xf + 4);                                   \
        for (int j = 0; j < 4; ++j) { pk[j] = (__bf16)lo[j]; pk[j+4] = (__bf16)hi[j]; } \
      }                                                                       \
      *(bf16x8*)(&XT[b][g * 512 + (row ^ g) * 8]) = pk;                       \
    } else {                                                                  \
      int j = i - 8;                                                          \
      gload16(Wt + (size_t)(ss) * 24576 + j * 512 + lane * 8,                 \
              &WTs[b][j * 512]);                                              \
    }                                                                         \
  }

  STAGE(0, 0);                           // preload step 0
  for (int s = 0; s < 16; ++s) {
    int cb = s & 1;
    __syncthreads();                     // must drain vmcnt here (global_load_lds -> LDS)
    if (s + 1 < 16) { STAGE(s + 1, cb ^ 1); }
#pragma unroll
    for (int t = 0; t < 2; ++t) {
      int g = t * 4 + quad;
      bf16x8 a = *(const bf16x8*)(&XT[cb][g * 512 + ((rowgrp * 16 + l16) ^ g) * 8]);
#pragma unroll
      for (int nt = 0; nt < 8; ++nt) {
        bf16x8 b = *(const bf16x8*)(&WTs[cb][(size_t)which * 8192 + g * 1024 + (nt * 16 + l16) * 8]);
        acc[nt] = __builtin_amdgcn_mfma_f32_16x16x32_bf16(a, b, acc[nt], 0, 0, 0);
      }
    }
  }
#undef STAGE

  int tile = row0 >> 6;
  if (which == 0) {
#pragma unroll
    for (int nt = 0; nt < 8; ++nt)
#pragma unroll
      for (int r = 0; r < 4; ++r) {
        int row = row0 + rowgrp * 16 + quad * 4 + r;
        q[(size_t)row * HH + nt * 16 + l16] = (__bf16)acc[nt][r];
      }
  } else if (which == 1) {
    __bf16* kb = ktl + (size_t)tile * 8192;
#pragma unroll
    for (int nt = 0; nt < 8; ++nt) {
      int h = nt * 16 + l16, g = h >> 3, j = h & 7;
#pragma unroll
      for (int r = 0; r < 4; ++r) {
        int sidx = rowgrp * 16 + quad * 4 + r;
        kb[g * 512 + sidx * 8 + j] = (__bf16)acc[nt][r];
      }
    }
  } else {
    __bf16* vb = vtl + (size_t)tile * 8192;
#pragma unroll
    for (int nt = 0; nt < 8; ++nt) {
      int h = nt * 16 + l16;
      int sb = rowgrp * 16 + quad * 4;
      bf16x4 pk;
#pragma unroll
      for (int r = 0; r < 4; ++r) pk[r] = (__bf16)acc[nt][r];
      *(bf16x4*)(vb + (sb >> 3) * 1024 + h * 8 + (sb & 7)) = pk;
    }
  }
}

// ------- flash attention: cooperative-pair split-K (R8 body, reverted) -------
// R9 lesson: cross-barrier register prefetch + asm fences -> allocator spilled
// the in-flight values (FETCH 11->124 MB); this body has no register headroom.
// R8 proven state: pairs share P via LDS, two-unit balance, XCD-batch swizzle,
// fixed-max softmax with plain-sum combine. 55.2 us measured.
// Known wall (cross-round analysis): ~2 MB/CU unique L1-miss flow at limited
// miss concurrency; next lever is gload16->LDS K/V streaming, not this body.
__global__ __launch_bounds__(768, 3) void flash_attn(
    const __bf16* __restrict__ q, const __bf16* __restrict__ ktl,
    const __bf16* __restrict__ vtl, void* __restrict__ out,
    const unsigned int* __restrict__ xw) {
  __shared__ __align__(16) __bf16 PLs[6][2][32 * PS]; // pair-shared P, dbuf, 55.3 KB
  __shared__ float CMB[4][32][132];                   // 4 partial-O sets, 67.6 KB
  __shared__ float CL[4][32];                         // partial l per set

  int bx = blockIdx.x;
  int batch = (bx & 7) >> 1;
  int qt0 = ((bx >> 3) << 1) | (bx & 1);

  int tid = threadIdx.x, lane = tid & 63, wave = tid >> 6;
  int p = wave >> 1, rw = wave & 1;      // 6 pairs x 2 col-half waves
  int l16 = lane & 15, quad = lane >> 4;

  int kA = (6 * (qt0 + 1) + 32) / 65;
  kA = max(1, min(5, kA));
  int qtB = 63 - qt0;
  int unit, kg, nkg, qtu, rbase;
  if (p < kA) { unit = 0; kg = p;      nkg = kA;     qtu = qt0; rbase = 0;  }
  else        { unit = 1; kg = p - kA; nkg = 6 - kA; qtu = qtB; rbase = 32; }

  int qb = qtu * 64;
  int MAXT = max(qt0 / kA + 1, qtB / (6 - kA) + 1);
  int mytrips = (qtu - kg) / nkg + 1;

  int isbf = probe_isbf(xw);

  const __bf16* qp  = q   + (size_t)batch * TT * HH;
  const __bf16* ktb = ktl + (size_t)batch * TT * HH;
  const __bf16* vtb = vtl + (size_t)batch * TT * HH;

  // Q fragments for all 32 rows of this unit (rows rbase..rbase+31)
  bf16x8 qf[2][4];
#pragma unroll
  for (int rg = 0; rg < 2; ++rg) {
    const __bf16* qrow = qp + (size_t)(qb + rbase + rg * 16 + l16) * HH + quad * 8;
#pragma unroll
    for (int ks = 0; ks < 4; ++ks) qf[rg][ks] = *(const bf16x8*)(qrow + ks * 32);
  }
  bf16x8 onesf;
#pragma unroll
  for (int j = 0; j < 8; ++j) onesf[j] = (l16 == 0) ? (__bf16)1.0f : (__bf16)0.0f;

  f32x4 acc_o[2][4] = {};                // [rowhalf][h-subtile within my 64-col half]
  f32x4 acc_l[2] = {};
  const float SC = 0.0450842200278f;     // log2(e)/32
  const float M0 = 4.0f;

  for (int t = 0; t < MAXT; ++t) {
    int jt = kg + t * nkg;
    int valid = (t < mytrips);
    int jtc = valid ? jt : kg;           // clamped safe tile for padded iters
    const __bf16* kt  = ktb + (size_t)jtc * 8192;
    const __bf16* vt2 = vtb + (size_t)jtc * 8192;

    // K fragments: only my 2 kn columns (8 KB instead of 16)
    bf16x8 kf[4][2];
#pragma unroll
    for (int ks = 0; ks < 4; ++ks)
#pragma unroll
      for (int kn = 0; kn < 2; ++kn)
        kf[ks][kn] = *(const bf16x8*)(kt + ((4 * ks + quad) * 64 + (rw * 2 + kn) * 16 + l16) * 8);

    // QK^T for all 32 rows x my 32 k-cols
    f32x4 accs[2][2] = {};
#pragma unroll
    for (int ks = 0; ks < 4; ++ks)
#pragma unroll
      for (int rg = 0; rg < 2; ++rg)
#pragma unroll
        for (int kn = 0; kn < 2; ++kn)
          accs[rg][kn] = __builtin_amdgcn_mfma_f32_16x16x32_bf16(qf[rg][ks], kf[ks][kn], accs[rg][kn], 0, 0, 0);

    // V fragments: only my 64-col h-half (8 KB); latency hidden by softmax+P-LDS
    bf16x8 vf[2][4];
#pragma unroll
    for (int ks2 = 0; ks2 < 2; ++ks2)
#pragma unroll
      for (int nt = 0; nt < 4; ++nt)
        vf[ks2][nt] = *(const bf16x8*)(vt2 + (ks2 * 4 + quad) * 1024 + (rw * 64 + nt * 16 + l16) * 8);

    // fixed-max softmax: p = exp2(s*SC - M0); mask only on diagonal tile
    float pv[2][2][4];
    if (valid && jt == qtu) {
#pragma unroll
      for (int rg = 0; rg < 2; ++rg)
#pragma unroll
        for (int kn = 0; kn < 2; ++kn) {
          int kcol = jt * 64 + (rw * 2 + kn) * 16 + l16;
          int qr0 = qb + rbase + rg * 16 + quad * 4;
#pragma unroll
          for (int r = 0; r < 4; ++r) {
            float z = fmaf(accs[rg][kn][r], SC, -M0);
            z = (kcol <= qr0 + r) ? z : MNEG;
            pv[rg][kn][r] = exp2f(z);
          }
        }
    } else if (valid) {
#pragma unroll
      for (int rg = 0; rg < 2; ++rg)
#pragma unroll
        for (int kn = 0; kn < 2; ++kn)
#pragma unroll
          for (int r = 0; r < 4; ++r)
            pv[rg][kn][r] = exp2f(fmaf(accs[rg][kn][r], SC, -M0));
    } else {
#pragma unroll
      for (int rg = 0; rg < 2; ++rg)
#pragma unroll
        for (int kn = 0; kn < 2; ++kn)
#pragma unroll
          for (int r = 0; r < 4; ++r)
            pv[rg][kn][r] = 0.0f;        // padded iter contributes nothing
    }

    // my P-half -> pair-shared LDS (32 rows x my 32 cols), buffer t&1
    __bf16* pw = &PLs[p][t & 1][0];
#pragma unroll
    for (int rg = 0; rg < 2; ++rg)
#pragma unroll
      for (int kn = 0; kn < 2; ++kn)
#pragma unroll
        for (int r = 0; r < 4; ++r)
          pw[(rg * 16 + quad * 4 + r) * PS + (rw * 2 + kn) * 16 + l16] = (__bf16)pv[rg][kn][r];

    __syncthreads();                     // pair P-halves visible; dbuf handles WAR

    // PV: all 32 rows (full P from LDS) x my 64 h-cols
#pragma unroll
    for (int ks2 = 0; ks2 < 2; ++ks2) {
      bf16x8 pa0 = *(const bf16x8*)(pw + l16 * PS + ks2 * 32 + quad * 8);
      bf16x8 pa1 = *(const bf16x8*)(pw + (16 + l16) * PS + ks2 * 32 + quad * 8);
      acc_l[0] = __builtin_amdgcn_mfma_f32_16x16x32_bf16(pa0, onesf, acc_l[0], 0, 0, 0);
      acc_l[1] = __builtin_amdgcn_mfma_f32_16x16x32_bf16(pa1, onesf, acc_l[1], 0, 0, 0);
#pragma unroll
      for (int nt = 0; nt < 4; ++nt) {
        acc_o[0][nt] = __builtin_amdgcn_mfma_f32_16x16x32_bf16(pa0, vf[ks2][nt], acc_o[0][nt], 0, 0, 0);
        acc_o[1][nt] = __builtin_amdgcn_mfma_f32_16x16x32_bf16(pa1, vf[ks2][nt], acc_o[1][nt], 0, 0, 0);
      }
    }
  }

  // ---- combine partials across pairs (plain sums; fixed-max => no rescale) ----
  // Slot map: unit A kg 1..kA-1 -> slots 0..kA-2; unit B kg 1..kB-1 -> kA-1..3.
  if (kg > 0) {
    int slot = (unit == 0) ? (kg - 1) : (kA - 1 + kg - 1);
#pragma unroll
    for (int rh = 0; rh < 2; ++rh)
#pragma unroll
      for (int nt = 0; nt < 4; ++nt)
#pragma unroll
        for (int r = 0; r < 4; ++r)
          CMB[slot][rh * 16 + quad * 4 + r][rw * 64 + nt * 16 + l16] = acc_o[rh][nt][r];
    if (rw == 0 && l16 == 0) {
#pragma unroll
      for (int rh = 0; rh < 2; ++rh)
#pragma unroll
        for (int r = 0; r < 4; ++r) CL[slot][rh * 16 + quad * 4 + r] = acc_l[rh][r];
    }
  }
  __syncthreads();
  if (kg == 0) {
    int lo  = (unit == 0) ? 0 : kA - 1;
    int cnt = (unit == 0) ? kA - 1 : 5 - kA;
    __bf16* ob = (__bf16*)out + (size_t)batch * TT * HH;
    float*  of = (float*)out  + (size_t)batch * TT * HH;
#pragma unroll
    for (int rh = 0; rh < 2; ++rh) {
      float inv[4];
#pragma unroll
      for (int r = 0; r < 4; ++r) {
        float lr = __shfl(acc_l[rh][r], lane & 48);
        for (int c = 0; c < cnt; ++c) lr += CL[lo + c][rh * 16 + quad * 4 + r];
        inv[r] = 1.f / fmaxf(lr, 1e-30f);
      }
#pragma unroll
      for (int nt = 0; nt < 4; ++nt)
#pragma unroll
        for (int r = 0; r < 4; ++r) {
          int row = qb + rbase + rh * 16 + quad * 4 + r;
          int col = rw * 64 + nt * 16 + l16;
          float val = acc_o[rh][nt][r];
          for (int c = 0; c < cnt; ++c) val += CMB[lo + c][rh * 16 + quad * 4 + r][col];
          val *= inv[r];
          size_t idx = (size_t)row * HH + col;
          if (isbf) ob[idx] = (__bf16)val;
          else      of[idx] = val;
        }
    }
  }
}

extern "C" void kernel_launch(void* const* d_in, const int* in_sizes, int n_in,
                              void* d_out, int out_size, void* d_ws, size_t ws_size,
                              hipStream_t stream) {
  const void* x  = d_in[0];
  const void* Wq = d_in[1];
  const void* Wk = d_in[2];
  const void* Wv = d_in[3];
  char* wsb = (char*)d_ws;
  __bf16* q   = (__bf16*)wsb;
  __bf16* ktl = q   + (size_t)NB * TT * HH;
  __bf16* vtl = ktl + (size_t)NB * TT * HH;
  __bf16* wt  = vtl + (size_t)NB * TT * HH;
  (void)ws_size; (void)in_sizes; (void)n_in; (void)out_size;

  transpose_w3<<<dim3(512, 3), 256, 0, stream>>>(Wq, Wk, Wv, wt,
                                                 (const unsigned int*)x);
  qkv_proj<<<256, 768, 0, stream>>>(x, wt, q, ktl, vtl);
  flash_attn<<<NB * 64, 768, 0, stream>>>(q, ktl, vtl, d_out,
                                          (const unsigned int*)x);
}